// Round 1
// baseline (740.208 us; speedup 1.0000x reference)
//
#include <hip/hip_runtime.h>
#include <hip/hip_bf16.h>

#define NUM_ADC_P 8
#define DENSE_L   1024
#define L_TILDE   64

typedef __attribute__((ext_vector_type(8))) short  short8;   // 8 bf16 = 4 VGPRs (MFMA A/B frag)
typedef __attribute__((ext_vector_type(4))) float  float4v;  // MFMA C/D frag

// ---------------------------------------------------------------------------
// Kernel 1: build Wt[n][k] = bf16( exp( -((k+1) - w_n)^2 / 100 ) )
// Layout: n-major, k contiguous  (64 rows x 1024 cols, bf16) -> 128 KB in d_ws.
// Tiny (65536 expf) — cost irrelevant, lives in L2/L3 for the GEMM kernel.
// ---------------------------------------------------------------------------
__global__ void build_w(const float* __restrict__ weight,
                        __hip_bfloat16* __restrict__ wt) {
    const int n = blockIdx.x;              // 64 blocks, one per sample position
    const float wn = weight[n];
    for (int k = threadIdx.x; k < DENSE_L; k += blockDim.x) {
        const float t = (float)(k + 1);
        const float d = t - wn;
        const float v = expf(-d * d * (1.0f / 100.0f));   // underflows to 0 for far l — fine
        wt[n * DENSE_L + k] = __float2bfloat16(v);
    }
}

// ---------------------------------------------------------------------------
// fp32 -> bf16 RTNE (bit trick; inputs are finite, no NaN path needed)
// ---------------------------------------------------------------------------
__device__ __forceinline__ short cvt_bf16(float f) {
    unsigned u = __builtin_bit_cast(unsigned, f);
    u += 0x7fffu + ((u >> 16) & 1u);
    return (short)(u >> 16);
}

__device__ __forceinline__ short8 cvt8(float4v a, float4v b) {
    short8 r;
    r[0] = cvt_bf16(a[0]); r[1] = cvt_bf16(a[1]);
    r[2] = cvt_bf16(a[2]); r[3] = cvt_bf16(a[3]);
    r[4] = cvt_bf16(b[0]); r[5] = cvt_bf16(b[1]);
    r[6] = cvt_bf16(b[2]); r[7] = cvt_bf16(b[3]);
    return r;
}

// ---------------------------------------------------------------------------
// Kernel 2: C[M=B*P, 64] = A[M,1024] * W[1024,64], bf16 MFMA, fp32 accumulate.
// Wave tile: 32 rows x 64 cols  (2 m-subtiles x 4 n-subtiles of 16x16x32).
// Block: 256 threads = 4 waves = 128 rows.  No LDS, no barriers.
//
// Fragment layout (m89/m91-verified gemm_bt pattern):
//   A frag: lane holds A[m0 + (lane&15)][k0 + (lane>>4)*8 + j], j=0..7
//   B frag: lane holds Wt[n0 + (lane&15)][k0 + (lane>>4)*8 + j]   (Wt = W^T)
//   D frag: D[m0 + (lane>>4)*4 + r][n0 + (lane&15)], r=0..3
// ---------------------------------------------------------------------------
__global__ __launch_bounds__(256, 4)
void sampling_gemm(const float* __restrict__ x,
                   const __hip_bfloat16* __restrict__ wt,
                   float* __restrict__ out) {
    const int lane = threadIdx.x & 63;
    const int wave = threadIdx.x >> 6;                    // 0..3
    const int r    = lane & 15;                            // row-in-tile / col-in-tile
    const int q    = lane >> 4;                            // quad 0..3

    const long m0 = (long)blockIdx.x * 128 + (long)wave * 32;

    const float* a0 = x + (m0 + r) * DENSE_L + q * 8;      // m-subtile 0 rows
    const float* a1 = a0 + 16 * DENSE_L;                   // m-subtile 1 rows
    const short* w0 = (const short*)wt + r * DENSE_L + q * 8;  // n-subtile 0 rows

    float4v acc[2][4];
    #pragma unroll
    for (int i = 0; i < 2; ++i)
        #pragma unroll
        for (int j = 0; j < 4; ++j)
            acc[i][j] = (float4v){0.f, 0.f, 0.f, 0.f};

    for (int kk = 0; kk < DENSE_L; kk += 32) {
        // A: 8 fp32 per m-subtile per lane (32 B contiguous)
        const float4v af0a = *(const float4v*)(a0 + kk);
        const float4v af0b = *(const float4v*)(a0 + kk + 4);
        const float4v af1a = *(const float4v*)(a1 + kk);
        const float4v af1b = *(const float4v*)(a1 + kk + 4);

        // B: 16 B per n-subtile per lane, served from L1/L2 (Wt is 128 KB, hot)
        short8 bf[4];
        #pragma unroll
        for (int ns = 0; ns < 4; ++ns)
            bf[ns] = *(const short8*)(w0 + ns * 16 * DENSE_L + kk);

        const short8 af0 = cvt8(af0a, af0b);
        const short8 af1 = cvt8(af1a, af1b);

        #pragma unroll
        for (int ns = 0; ns < 4; ++ns) {
            acc[0][ns] = __builtin_amdgcn_mfma_f32_16x16x32_bf16(af0, bf[ns], acc[0][ns], 0, 0, 0);
            acc[1][ns] = __builtin_amdgcn_mfma_f32_16x16x32_bf16(af1, bf[ns], acc[1][ns], 0, 0, 0);
        }
    }

    // Epilogue: D[m = q*4 + rr][n = lane&15] per 16x16 subtile.
    #pragma unroll
    for (int ms = 0; ms < 2; ++ms) {
        #pragma unroll
        for (int ns = 0; ns < 4; ++ns) {
            #pragma unroll
            for (int rr = 0; rr < 4; ++rr) {
                out[(m0 + ms * 16 + q * 4 + rr) * L_TILDE + ns * 16 + r] = acc[ms][ns][rr];
            }
        }
    }
}

// ---------------------------------------------------------------------------
extern "C" void kernel_launch(void* const* d_in, const int* in_sizes, int n_in,
                              void* d_out, int out_size, void* d_ws, size_t ws_size,
                              hipStream_t stream) {
    const float* x      = (const float*)d_in[0];   // [B, P*L] fp32
    const float* weight = (const float*)d_in[1];   // [64] fp32
    float* out          = (float*)d_out;           // [B, P*64] fp32
    __hip_bfloat16* wt  = (__hip_bfloat16*)d_ws;   // [64][1024] bf16 = 128 KB

    // M = total rows of the implicit GEMM = B * NUM_ADC_P
    const int M = in_sizes[0] / DENSE_L;           // 131072
    const int grid = M / 128;                      // 128 rows per block

    build_w<<<64, 256, 0, stream>>>(weight, wt);
    sampling_gemm<<<grid, 256, 0, stream>>>(x, wt, out);
}

// Round 2
// 703.750 us; speedup vs baseline: 1.0518x; 1.0518x over previous
//
#include <hip/hip_runtime.h>
#include <hip/hip_bf16.h>

#define NUM_ADC_P 8
#define DENSE_L   1024
#define L_TILDE   64

typedef __attribute__((ext_vector_type(8))) short  short8;   // 8 bf16 = 4 VGPRs (MFMA A/B frag)
typedef __attribute__((ext_vector_type(4))) float  float4v;  // MFMA C/D frag

// ws layout: [0, 128 KiB) = wt bf16[64][1024] ; [128 KiB, +32 B) = int ranges[8]
// ranges[2g] / ranges[2g+1] = first / last (inclusive) 32-wide k-slab needed by
// output-column group g (columns 16g..16g+15).

// ---------------------------------------------------------------------------
// Kernel 1: Wt[n][k] = bf16(exp(-((k+1)-w_n)^2/100)), n-major (Wt = W^T),
// plus per-16-column-group k-slab ranges (|d| <= ~48 cutoff; exp(-23)~1e-10,
// far below bf16 resolution and the 0.38 absmax threshold).
// ---------------------------------------------------------------------------
__global__ void build_w(const float* __restrict__ weight,
                        __hip_bfloat16* __restrict__ wt,
                        int* __restrict__ ranges) {
    const int n = blockIdx.x;              // 64 blocks, one per sample position
    const float wn = weight[n];
    for (int k = threadIdx.x; k < DENSE_L; k += blockDim.x) {
        const float t = (float)(k + 1);
        const float d = t - wn;
        wt[n * DENSE_L + k] = __float2bfloat16(expf(-d * d * 0.01f));
    }
    if (blockIdx.x == 0 && threadIdx.x < 4) {
        const int g = threadIdx.x;
        float wmin = 1e30f, wmax = -1e30f;
        for (int j = 0; j < 16; ++j) {          // no monotonicity assumption
            const float w = weight[g * 16 + j];
            wmin = fminf(wmin, w);
            wmax = fmaxf(wmax, w);
        }
        int klo = (int)floorf(wmin) - 49; if (klo < 0) klo = 0;
        int khi = (int)ceilf(wmax) + 48;  if (khi > DENSE_L - 1) khi = DENSE_L - 1;
        ranges[2 * g]     = klo >> 5;           // first slab
        ranges[2 * g + 1] = khi >> 5;           // last slab (inclusive)
    }
}

// ---------------------------------------------------------------------------
// 8x fp32 -> bf16 via packed HW convert (v_cvt_pk_bf16_f32 on gfx950): 4 insts
// per 8 elements instead of ~24 with the bit-trick. RTNE either way.
// ---------------------------------------------------------------------------
__device__ __forceinline__ short8 cvt8(float4v a, float4v b) {
    union { short8 s; __hip_bfloat162 h[4]; } u;
    u.h[0] = __float22bfloat162_rn(make_float2(a[0], a[1]));
    u.h[1] = __float22bfloat162_rn(make_float2(a[2], a[3]));
    u.h[2] = __float22bfloat162_rn(make_float2(b[0], b[1]));
    u.h[3] = __float22bfloat162_rn(make_float2(b[2], b[3]));
    return u.s;
}

__device__ __forceinline__ float4v ldnt(const float* p) {
    return __builtin_nontemporal_load((const float4v*)p);
}

// ---------------------------------------------------------------------------
// Kernel 2: C[M,64] = A[M,1024] * W[1024,64], bf16 MFMA fp32-acc, no LDS.
// Wave tile 32x64 (2 m-subtiles x 4 n-subtiles of 16x16x32). Banded: per
// n-subtile only its k-slab range is computed. A prefetched one slab ahead.
//
// Fragment layout (verified R1, absmax 0.125):
//   A frag: lane holds A[m0 + (lane&15)][32*kk + (lane>>4)*8 + j], j=0..7
//   B frag: lane holds Wt[n0 + (lane&15)][32*kk + (lane>>4)*8 + j]
//   D frag: D[m0 + (lane>>4)*4 + rr][n0 + (lane&15)], rr=0..3
// ---------------------------------------------------------------------------
__global__ __launch_bounds__(256, 4)
void sampling_gemm(const float* __restrict__ x,
                   const __hip_bfloat16* __restrict__ wt,
                   const int* __restrict__ ranges,
                   float* __restrict__ out) {
    const int lane = threadIdx.x & 63;
    const int wave = threadIdx.x >> 6;                    // 0..3
    const int r    = lane & 15;
    const int q    = lane >> 4;                           // quad 0..3

    const long m0 = (long)blockIdx.x * 128 + (long)wave * 32;

    const float* a0 = x + (m0 + r) * DENSE_L + q * 8;     // m-subtile 0 row
    const float* a1 = a0 + 16 * DENSE_L;                  // m-subtile 1 row
    const short* w0 = (const short*)wt + r * DENSE_L + q * 8;

    // wave-uniform slab ranges per n-subtile (scalar loads + scalar branches)
    const int lo0 = ranges[0], hi0 = ranges[1];
    const int lo1 = ranges[2], hi1 = ranges[3];
    const int lo2 = ranges[4], hi2 = ranges[5];
    const int lo3 = ranges[6], hi3 = ranges[7];

    float4v acc[2][4];
    #pragma unroll
    for (int i = 0; i < 2; ++i)
        #pragma unroll
        for (int j = 0; j < 4; ++j)
            acc[i][j] = (float4v){0.f, 0.f, 0.f, 0.f};

    // prefetch slab 0
    float4v c0a = ldnt(a0), c0b = ldnt(a0 + 4);
    float4v c1a = ldnt(a1), c1b = ldnt(a1 + 4);

    for (int kk = 0; kk < 32; ++kk) {
        // issue next slab's A loads before consuming current (compiler emits
        // partial vmcnt wait for the current 4 only)
        const int kn = (kk + 1) & 31;                     // wraps: harmless reload
        const float4v n0a = ldnt(a0 + kn * 32);
        const float4v n0b = ldnt(a0 + kn * 32 + 4);
        const float4v n1a = ldnt(a1 + kn * 32);
        const float4v n1b = ldnt(a1 + kn * 32 + 4);

        const short8 af0 = cvt8(c0a, c0b);
        const short8 af1 = cvt8(c1a, c1b);
        const short* wk = w0 + kk * 32;

        if (kk >= lo0 && kk <= hi0) {
            const short8 b = *(const short8*)(wk);
            acc[0][0] = __builtin_amdgcn_mfma_f32_16x16x32_bf16(af0, b, acc[0][0], 0, 0, 0);
            acc[1][0] = __builtin_amdgcn_mfma_f32_16x16x32_bf16(af1, b, acc[1][0], 0, 0, 0);
        }
        if (kk >= lo1 && kk <= hi1) {
            const short8 b = *(const short8*)(wk + 16 * DENSE_L);
            acc[0][1] = __builtin_amdgcn_mfma_f32_16x16x32_bf16(af0, b, acc[0][1], 0, 0, 0);
            acc[1][1] = __builtin_amdgcn_mfma_f32_16x16x32_bf16(af1, b, acc[1][1], 0, 0, 0);
        }
        if (kk >= lo2 && kk <= hi2) {
            const short8 b = *(const short8*)(wk + 32 * DENSE_L);
            acc[0][2] = __builtin_amdgcn_mfma_f32_16x16x32_bf16(af0, b, acc[0][2], 0, 0, 0);
            acc[1][2] = __builtin_amdgcn_mfma_f32_16x16x32_bf16(af1, b, acc[1][2], 0, 0, 0);
        }
        if (kk >= lo3 && kk <= hi3) {
            const short8 b = *(const short8*)(wk + 48 * DENSE_L);
            acc[0][3] = __builtin_amdgcn_mfma_f32_16x16x32_bf16(af0, b, acc[0][3], 0, 0, 0);
            acc[1][3] = __builtin_amdgcn_mfma_f32_16x16x32_bf16(af1, b, acc[1][3], 0, 0, 0);
        }

        c0a = n0a; c0b = n0b; c1a = n1a; c1b = n1b;
    }

    // Epilogue: D[m = q*4 + rr][n = ns*16 + r]; streaming stores.
    #pragma unroll
    for (int ms = 0; ms < 2; ++ms) {
        #pragma unroll
        for (int ns = 0; ns < 4; ++ns) {
            #pragma unroll
            for (int rr = 0; rr < 4; ++rr) {
                __builtin_nontemporal_store(
                    acc[ms][ns][rr],
                    out + (m0 + ms * 16 + q * 4 + rr) * L_TILDE + ns * 16 + r);
            }
        }
    }
}

// ---------------------------------------------------------------------------
extern "C" void kernel_launch(void* const* d_in, const int* in_sizes, int n_in,
                              void* d_out, int out_size, void* d_ws, size_t ws_size,
                              hipStream_t stream) {
    const float* x      = (const float*)d_in[0];   // [B, P*L] fp32
    const float* weight = (const float*)d_in[1];   // [64] fp32
    float* out          = (float*)d_out;           // [B, P*64] fp32
    __hip_bfloat16* wt  = (__hip_bfloat16*)d_ws;   // [64][1024] bf16 = 128 KiB
    int* ranges         = (int*)((char*)d_ws + 64 * DENSE_L * sizeof(__hip_bfloat16));

    const int M = in_sizes[0] / DENSE_L;           // B * NUM_ADC_P = 131072
    const int grid = M / 128;                      // 128 rows per block

    build_w<<<64, 256, 0, stream>>>(weight, wt, ranges);
    sampling_gemm<<<grid, 256, 0, stream>>>(x, wt, ranges, out);
}